// Round 2
// baseline (353.700 us; speedup 1.0000x reference)
//
#include <hip/hip_runtime.h>
#include <hip/hip_fp16.h>

// Q4_0-style dequant with the harness's int32-widened input:
// the reference's uint8 raw_data arrives as one int32 PER BYTE
// ("integer -> const int*"), so block b occupies raw32[b*18 .. b*18+17]:
//   elements 0,1   : low bytes of the fp16 scale (little-endian)
//   elements 2..17 : the 16 packed quant bytes
// out[b*32 + j]      = scale * ((byte_j & 15) - 8)   j in [0,16)
// out[b*32 + 16 + j] = scale * ((byte_j >> 4) - 8)
//
// Mapping: thread t -> block b = t>>3, slot k = t&7; writes one float4 at
// out[b*32 + k*4]. k<4 -> low nibbles of bytes 4k..4k+3; k>=4 -> high
// nibbles of the same bytes. Element index 18b+2+4(k&3) is always even ->
// 8-byte aligned -> int2 (dwordx2) loads are safe.

constexpr long long NUMEL = 8192LL * 8192LL;
constexpr int QK = 32;
constexpr long long NBLOCKS = NUMEL / QK;          // 2,097,152
constexpr int BLOCK_INTS = 18;                     // int32 elements per block

__global__ __launch_bounds__(256)
void dequant_q4_kernel(const int* __restrict__ raw32,
                       float4* __restrict__ out4)
{
    const int t = blockIdx.x * 256 + threadIdx.x;   // one thread per output float4
    const int b = t >> 3;                           // source quant block
    const int k = t & 7;                            // sub-slot within block

    const int base = b * BLOCK_INTS;                // max ~37.7M, fits int

    // fp16 scale from the low bytes of elements 0,1 (little-endian)
    const int s_lo = raw32[base]     & 0xff;
    const int s_hi = raw32[base + 1] & 0xff;
    const unsigned short s16 = (unsigned short)(s_lo | (s_hi << 8));
    const float scale = __half2float(__ushort_as_half(s16));

    // 4 quant bytes for this slot = 4 consecutive int32s, as two int2 loads
    const int j = (k & 3) * 4;
    const int2 q01 = *(const int2*)(raw32 + base + 2 + j);
    const int2 q23 = *(const int2*)(raw32 + base + 2 + j + 2);

    const int sh = (k >= 4) ? 4 : 0;                // low vs high nibble

    float4 o;
    o.x = scale * (float)(((q01.x >> sh) & 15) - 8);
    o.y = scale * (float)(((q01.y >> sh) & 15) - 8);
    o.z = scale * (float)(((q23.x >> sh) & 15) - 8);
    o.w = scale * (float)(((q23.y >> sh) & 15) - 8);

    out4[t] = o;
}

extern "C" void kernel_launch(void* const* d_in, const int* in_sizes, int n_in,
                              void* d_out, int out_size, void* d_ws, size_t ws_size,
                              hipStream_t stream)
{
    const int* raw32 = (const int*)d_in[0];
    float4* out4 = (float4*)d_out;

    const long long n_threads = NUMEL / 4;          // 16,777,216 float4 stores
    const int block = 256;
    const long long grid = n_threads / block;       // 65,536 blocks

    dequant_q4_kernel<<<dim3((unsigned)grid), dim3(block), 0, stream>>>(raw32, out4);
}

// Round 3
// 351.978 us; speedup vs baseline: 1.0049x; 1.0049x over previous
//
#include <hip/hip_runtime.h>
#include <hip/hip_fp16.h>

// Q4_0-style dequant, harness delivers raw_data as one int32 PER BYTE.
// Block b occupies raw32[b*18 .. b*18+17]:
//   ints 0,1   : low bytes of the fp16 scale (little-endian)
//   ints 2..17 : the 16 packed quant bytes
// out[b*32 + j]      = scale * ((byte_j & 15) - 8)   j in [0,16)
// out[b*32 + 16 + j] = scale * ((byte_j >> 4) - 8)
//
// LDS-staged version: each 256-thread workgroup owns 32 quant blocks =
// 576 contiguous int32 (2304 B, 64 B-aligned since 576 % 16 == 0).
// Stage: threads 0..143 each load one int4 (global_load_dwordx4, perfectly
// coalesced, no duplication). Compute: thread tid -> local block bl=tid>>3,
// slot k=tid&7, reads scale (int2) + 4 quant ints (2x int2) from LDS
// (8 B-aligned: 18*bl+2+4*(k&3) is even), writes one coalesced float4.

constexpr long long NUMEL = 8192LL * 8192LL;
constexpr int QK = 32;
constexpr long long NBLOCKS = NUMEL / QK;     // 2,097,152
constexpr int BLOCK_INTS = 18;                // int32 elements per quant block
constexpr int WG_BLOCKS = 32;                 // quant blocks per workgroup
constexpr int WG_INTS = WG_BLOCKS * BLOCK_INTS;  // 576

__global__ __launch_bounds__(256)
void dequant_q4_kernel(const int* __restrict__ raw32,
                       float4* __restrict__ out4)
{
    __shared__ int lds[WG_INTS];

    const int tid = threadIdx.x;
    const long long wg = blockIdx.x;

    // ---- stage 2304 B of input, fully coalesced ----
    if (tid < WG_INTS / 4) {                   // 144 int4 loads
        const int4 v = *(const int4*)(raw32 + wg * WG_INTS + (long long)tid * 4);
        ((int4*)lds)[tid] = v;
    }
    __syncthreads();

    // ---- dequant ----
    const int bl = tid >> 3;                   // local quant block 0..31
    const int k  = tid & 7;                    // sub-slot
    const int base = bl * BLOCK_INTS;

    // fp16 scale from low bytes of ints 0,1 (base*4 bytes = 72*bl, 8-aligned)
    const int2 s = *(const int2*)(lds + base);
    const unsigned short s16 = (unsigned short)((s.x & 0xff) | ((s.y & 0xff) << 8));
    const float scale = __half2float(__ushort_as_half(s16));

    // 4 quant bytes for this slot = 4 consecutive ints, two int2 reads
    const int j = (k & 3) * 4;
    const int2 q01 = *(const int2*)(lds + base + 2 + j);
    const int2 q23 = *(const int2*)(lds + base + 4 + j);

    const int sh = (k >= 4) ? 4 : 0;           // low vs high nibble

    float4 o;
    o.x = scale * (float)(((q01.x >> sh) & 15) - 8);
    o.y = scale * (float)(((q01.y >> sh) & 15) - 8);
    o.z = scale * (float)(((q23.x >> sh) & 15) - 8);
    o.w = scale * (float)(((q23.y >> sh) & 15) - 8);

    out4[wg * 256 + tid] = o;
}

extern "C" void kernel_launch(void* const* d_in, const int* in_sizes, int n_in,
                              void* d_out, int out_size, void* d_ws, size_t ws_size,
                              hipStream_t stream)
{
    const int* raw32 = (const int*)d_in[0];
    float4* out4 = (float4*)d_out;

    const long long n_wg = NBLOCKS / WG_BLOCKS;   // 65,536 workgroups
    dequant_q4_kernel<<<dim3((unsigned)n_wg), dim3(256), 0, stream>>>(raw32, out4);
}